// Round 3
// baseline (1223.747 us; speedup 1.0000x reference)
//
#include <hip/hip_runtime.h>

#define N_MI 100000
#define N_DI 50000
#define MI_P 100352   // multiple of 256
#define DI_P 50176    // multiple of 256

typedef _Float16 half8  __attribute__((ext_vector_type(8)));
typedef _Float16 half4  __attribute__((ext_vector_type(4)));
typedef _Float16 half2v __attribute__((ext_vector_type(2)));
typedef float    floatx4 __attribute__((ext_vector_type(4)));

// ---------------------------------------------------------------------------
// CSR build
// ---------------------------------------------------------------------------
__global__ void count_kernel(const int* __restrict__ src, const int* __restrict__ dst,
                             int* deg_mi, int* deg_di, int E) {
    int i = blockIdx.x * blockDim.x + threadIdx.x;
    if (i < E) {
        atomicAdd(&deg_mi[src[i]], 1);
        atomicAdd(&deg_di[dst[i]], 1);
    }
}

__global__ __launch_bounds__(1024) void scan_kernel(const int* __restrict__ deg_di,
                                                    const int* __restrict__ deg_mi,
                                                    int* row_di, int* row_mi) {
    const int* deg;
    int* row;
    int n;
    if (blockIdx.x == 0) { deg = deg_di; row = row_di; n = N_DI; }
    else                 { deg = deg_mi; row = row_mi; n = N_MI; }

    __shared__ int wsum[16];
    int t = threadIdx.x;
    int lane = t & 63;
    int w = t >> 6;
    int carry = 0;

    for (int base = 0; base < n; base += 1024) {
        int i = base + t;
        int v = (i < n) ? deg[i] : 0;
        int x = v;
        #pragma unroll
        for (int off = 1; off < 64; off <<= 1) {
            int y = __shfl_up(x, off, 64);
            if (lane >= off) x += y;
        }
        if (lane == 63) wsum[w] = x;
        __syncthreads();
        if (w == 0 && lane < 16) {
            int s = wsum[lane];
            #pragma unroll
            for (int off = 1; off < 16; off <<= 1) {
                int y = __shfl_up(s, off, 16);
                if (lane >= off) s += y;
            }
            wsum[lane] = s;
        }
        __syncthreads();
        int woff = (w == 0) ? 0 : wsum[w - 1];
        int incl = x + woff;
        if (i < n) row[i] = carry + incl - v;
        carry += wsum[15];
        __syncthreads();
    }
    if (t == 0) row[n] = carry;
}

__global__ void fill_kernel(const int* __restrict__ src, const int* __restrict__ dst,
                            const int* __restrict__ row_mi, const int* __restrict__ row_di,
                            int* cur_mi, int* cur_di, int* csr_mi, int* csr_di, int E) {
    int i = blockIdx.x * blockDim.x + threadIdx.x;
    if (i >= E) return;
    int s = src[i], d = dst[i];
    int p = atomicAdd(&cur_di[d], 1);
    csr_di[row_di[d] + p] = s;
    int q = atomicAdd(&cur_mi[s], 1);
    csr_mi[row_mi[s] + q] = d;
}

// ---------------------------------------------------------------------------
// fp32 -> fp16 weight converts (14 small arrays, one launch)
// ---------------------------------------------------------------------------
struct Cvt14 {
    const float* s[14];
    _Float16* d[14];
    int n4[14];
};

__global__ void cvt14_kernel(Cvt14 a) {
    int arr = blockIdx.y;
    int i = blockIdx.x * blockDim.x + threadIdx.x;
    if (i < a.n4[arr]) {
        float4 v = ((const float4*)a.s[arr])[i];
        half4 h = {(_Float16)v.x, (_Float16)v.y, (_Float16)v.z, (_Float16)v.w};
        ((half4*)a.d[arr])[i] = h;
    }
}

// ---------------------------------------------------------------------------
// Mean aggregation (fp16 in/out, fp32 accumulate). 4 nodes / 256-thr block.
// ---------------------------------------------------------------------------
__global__ __launch_bounds__(256) void agg_kernel(const _Float16* __restrict__ hsrc,
                                                  const int* __restrict__ row,
                                                  const int* __restrict__ csr,
                                                  _Float16* __restrict__ out,
                                                  int din, int n) {
    int node = blockIdx.x * 4 + (threadIdx.x >> 6);
    if (node >= n) return;
    int t = threadIdx.x & 63;
    int beg = row[node], end = row[node + 1];
    int two = (din >> 7) > 1;
    float sx0 = 0.f, sy0 = 0.f, sx1 = 0.f, sy1 = 0.f;
    for (int j = beg; j < end; ++j) {
        const half2v* p = (const half2v*)(hsrc + (long)csr[j] * din);
        half2v v0 = p[t];
        sx0 += (float)v0.x; sy0 += (float)v0.y;
        if (two) {
            half2v v1 = p[t + 64];
            sx1 += (float)v1.x; sy1 += (float)v1.y;
        }
    }
    float inv = 1.f / (float)max(end - beg, 1);
    half2v* o = (half2v*)(out + (long)node * din);
    half2v w0; w0.x = (_Float16)(sx0 * inv); w0.y = (_Float16)(sy0 * inv);
    o[t] = w0;
    if (two) {
        half2v w1; w1.x = (_Float16)(sx1 * inv); w1.y = (_Float16)(sy1 * inv);
        o[t + 64] = w1;
    }
}

// ---------------------------------------------------------------------------
// Register-direct fp16 MFMA GEMM (no LDS, no barriers).
// Wave tile: (MW*16) x 64. Block = 4 waves stacked along M.
// A fragment: lane m = lane&15, k-chunk = quad*8 -> one half8 global load.
// W fragment: lane n = lane&15, same -> W is [N x K] row-major, cache-resident.
// ---------------------------------------------------------------------------
template<int MW>
__device__ __forceinline__ void pass_f16(const _Float16* __restrict__ A,
                                         const _Float16* __restrict__ W,
                                         int K, long mbase, int n0, int lr, int quad,
                                         floatx4 (&acc)[MW][4]) {
    #pragma unroll 2
    for (int k0 = 0; k0 < K; k0 += 32) {
        half8 bf[4];
        #pragma unroll
        for (int j = 0; j < 4; ++j)
            bf[j] = *(const half8*)(W + (long)(n0 + j * 16 + lr) * K + k0 + quad * 8);
        half8 af[MW];
        #pragma unroll
        for (int i = 0; i < MW; ++i)
            af[i] = *(const half8*)(A + (mbase + i * 16 + lr) * K + k0 + quad * 8);
        #pragma unroll
        for (int i = 0; i < MW; ++i)
            #pragma unroll
            for (int j = 0; j < 4; ++j)
                acc[i][j] = __builtin_amdgcn_mfma_f32_16x16x32_f16(af[i], bf[j], acc[i][j], 0, 0, 0);
    }
}

template<int MW>
__device__ __forceinline__ void pass_f32(const float* __restrict__ A,
                                         const _Float16* __restrict__ W,
                                         int M, int K, long mbase, int n0, int lr, int quad,
                                         floatx4 (&acc)[MW][4]) {
    #pragma unroll 2
    for (int k0 = 0; k0 < K; k0 += 32) {
        half8 bf[4];
        #pragma unroll
        for (int j = 0; j < 4; ++j)
            bf[j] = *(const half8*)(W + (long)(n0 + j * 16 + lr) * K + k0 + quad * 8);
        half8 af[MW];
        #pragma unroll
        for (int i = 0; i < MW; ++i) {
            long m = mbase + i * 16 + lr;
            if (m > M - 1) m = M - 1;           // inputs are exact-sized: clamp
            const float* a = A + m * K + k0 + quad * 8;
            float4 u = *(const float4*)a;
            float4 v = *(const float4*)(a + 4);
            half8 h = {(_Float16)u.x, (_Float16)u.y, (_Float16)u.z, (_Float16)u.w,
                       (_Float16)v.x, (_Float16)v.y, (_Float16)v.z, (_Float16)v.w};
            af[i] = h;
        }
        #pragma unroll
        for (int i = 0; i < MW; ++i)
            #pragma unroll
            for (int j = 0; j < 4; ++j)
                acc[i][j] = __builtin_amdgcn_mfma_f32_16x16x32_f16(af[i], bf[j], acc[i][j], 0, 0, 0);
    }
}

template<int MW, bool AF32>
__global__ __launch_bounds__(256) void hgemm_reg(
    const void* __restrict__ A1v, const _Float16* __restrict__ W1,
    const _Float16* __restrict__ A2, const _Float16* __restrict__ W2,
    const float* __restrict__ bias, const float* __restrict__ Cadd,
    _Float16* __restrict__ C, int M, int N, int K, int relu)
{
    const int wave = threadIdx.x >> 6, lane = threadIdx.x & 63;
    const int quad = lane >> 4, lr = lane & 15;
    const long mbase = (long)blockIdx.x * (64 * MW) + wave * (16 * MW);
    const int n0 = blockIdx.y * 64;

    floatx4 acc[MW][4] = {};

    if (AF32)
        pass_f32<MW>((const float*)A1v, W1, M, K, mbase, n0, lr, quad, acc);
    else
        pass_f16<MW>((const _Float16*)A1v, W1, K, mbase, n0, lr, quad, acc);
    if (A2)
        pass_f16<MW>(A2, W2, K, mbase, n0, lr, quad, acc);

    // epilogue: C/D layout col = lane&15 (n), row = quad*4+reg (m)
    #pragma unroll
    for (int i = 0; i < MW; ++i) {
        int mb = (int)mbase + i * 16 + quad * 4;
        #pragma unroll
        for (int j = 0; j < 4; ++j) {
            int n = n0 + j * 16 + lr;
            float bn = bias[n];
            #pragma unroll
            for (int r = 0; r < 4; ++r) {
                int m = mb + r;
                if (m < M) {
                    float v = acc[i][j][r] + bn;
                    if (Cadd) v += Cadd[(long)m * N + n];
                    if (relu) v = fmaxf(v, 0.f);
                    C[(long)m * N + n] = (_Float16)v;
                }
            }
        }
    }
}

// ---------------------------------------------------------------------------
// Classifier: out[e] = dot64(h_mi[ls[e]], h_di[ld[e]]), fp16 in, fp32 out
// ---------------------------------------------------------------------------
__global__ void classify_kernel(const _Float16* __restrict__ hmi, const _Float16* __restrict__ hdi,
                                const int* __restrict__ ls, const int* __restrict__ ld,
                                float* __restrict__ out, int L) {
    long idx = (long)blockIdx.x * blockDim.x + threadIdx.x;
    int e = (int)(idx >> 4), q = (int)(idx & 15);
    if (e >= L) return;
    const half4* ra = (const half4*)(hmi + (long)ls[e] * 64);
    const half4* rb = (const half4*)(hdi + (long)ld[e] * 64);
    half4 a = ra[q], b = rb[q];
    float s = (float)a.x * (float)b.x + (float)a.y * (float)b.y +
              (float)a.z * (float)b.z + (float)a.w * (float)b.w;
    #pragma unroll
    for (int off = 8; off >= 1; off >>= 1) s += __shfl_down(s, off, 16);
    if (q == 0) out[e] = s;
}

// ---------------------------------------------------------------------------
// Launch
// ---------------------------------------------------------------------------
extern "C" void kernel_launch(void* const* d_in, const int* in_sizes, int n_in,
                              void* d_out, int out_size, void* d_ws, size_t ws_size,
                              hipStream_t stream) {
    const float* x_mi   = (const float*)d_in[0];
    const float* x_di   = (const float*)d_in[1];
    const float* W_mi   = (const float*)d_in[2];
    const float* b_mi   = (const float*)d_in[3];
    const float* W_di   = (const float*)d_in[4];
    const float* b_di   = (const float*)d_in[5];
    const float* emb_mi = (const float*)d_in[6];
    const float* emb_di = (const float*)d_in[7];
    const float* Wl1_md = (const float*)d_in[8];
    const float* bl1_md = (const float*)d_in[9];
    const float* Wr1_md = (const float*)d_in[10];
    const float* Wl1_dm = (const float*)d_in[11];
    const float* bl1_dm = (const float*)d_in[12];
    const float* Wr1_dm = (const float*)d_in[13];
    const float* Wl2_md = (const float*)d_in[14];
    const float* bl2_md = (const float*)d_in[15];
    const float* Wr2_md = (const float*)d_in[16];
    const float* Wl2_dm = (const float*)d_in[17];
    const float* bl2_dm = (const float*)d_in[18];
    const float* Wr2_dm = (const float*)d_in[19];
    const float* Wl3_md = (const float*)d_in[20];
    const float* bl3_md = (const float*)d_in[21];
    const float* Wr3_md = (const float*)d_in[22];
    const float* Wl3_dm = (const float*)d_in[23];
    const float* bl3_dm = (const float*)d_in[24];
    const float* Wr3_dm = (const float*)d_in[25];
    const int* edge_src  = (const int*)d_in[26];
    const int* edge_dst  = (const int*)d_in[27];
    const int* label_src = (const int*)d_in[28];
    const int* label_dst = (const int*)d_in[29];
    const int E = in_sizes[26];
    const int L = in_sizes[28];
    float* out = (float*)d_out;

    // ---- workspace layout (fp16 first, then ints) ----
    _Float16* hp = (_Float16*)d_ws;
    _Float16* wWmi  = hp; hp += 128 * 256;
    _Float16* wWdi  = hp; hp += 128 * 128;
    _Float16* wl1md = hp; hp += 256 * 128;
    _Float16* wr1md = hp; hp += 256 * 128;
    _Float16* wl1dm = hp; hp += 256 * 128;
    _Float16* wr1dm = hp; hp += 256 * 128;
    _Float16* wl2md = hp; hp += 128 * 256;
    _Float16* wr2md = hp; hp += 128 * 256;
    _Float16* wl2dm = hp; hp += 128 * 256;
    _Float16* wr2dm = hp; hp += 128 * 256;
    _Float16* wl3md = hp; hp += 64 * 128;
    _Float16* wr3md = hp; hp += 64 * 128;
    _Float16* wl3dm = hp; hp += 64 * 128;
    _Float16* wr3dm = hp; hp += 64 * 128;
    _Float16* h_mi0 = hp; hp += (long)MI_P * 256;
    _Float16* h_mi1 = hp; hp += (long)MI_P * 256;
    _Float16* h_di0 = hp; hp += (long)DI_P * 256;
    _Float16* h_di1 = hp; hp += (long)DI_P * 256;
    _Float16* aggh  = hp; hp += (long)MI_P * 256;

    int* ip = (int*)hp;
    int* deg_di = ip;  ip += N_DI;
    int* deg_mi = ip;  ip += N_MI;
    int* cur_di = ip;  ip += N_DI;
    int* cur_mi = ip;  ip += N_MI;
    int* row_di = ip;  ip += N_DI + 1;
    int* row_mi = ip;  ip += N_MI + 1;
    int* csr_di = ip;  ip += E;
    int* csr_mi = ip;  ip += E;

    // ---- CSR build ----
    hipMemsetAsync(deg_di, 0, (size_t)(2 * (N_DI + N_MI)) * sizeof(int), stream);
    int eb = (E + 255) / 256;
    count_kernel<<<eb, 256, 0, stream>>>(edge_src, edge_dst, deg_mi, deg_di, E);
    scan_kernel<<<2, 1024, 0, stream>>>(deg_di, deg_mi, row_di, row_mi);
    fill_kernel<<<eb, 256, 0, stream>>>(edge_src, edge_dst, row_mi, row_di,
                                        cur_mi, cur_di, csr_mi, csr_di, E);

    // ---- weight converts (x converts fused into init GEMMs) ----
    Cvt14 cv;
    const float* srcs[14] = {W_mi, W_di, Wl1_md, Wr1_md, Wl1_dm, Wr1_dm,
                             Wl2_md, Wr2_md, Wl2_dm, Wr2_dm, Wl3_md, Wr3_md, Wl3_dm, Wr3_dm};
    _Float16* dsts[14] = {wWmi, wWdi, wl1md, wr1md, wl1dm, wr1dm,
                          wl2md, wr2md, wl2dm, wr2dm, wl3md, wr3md, wl3dm, wr3dm};
    int ns[14] = {32768, 16384, 32768, 32768, 32768, 32768,
                  32768, 32768, 32768, 32768, 8192, 8192, 8192, 8192};
    for (int i = 0; i < 14; ++i) { cv.s[i] = srcs[i]; cv.d[i] = dsts[i]; cv.n4[i] = ns[i] / 4; }
    cvt14_kernel<<<dim3(32, 14), 256, 0, stream>>>(cv);

    // ---- init: h0 = x @ W^T + b + emb  (fp32 A loaded+converted in-kernel) ----
    hgemm_reg<2, true><<<dim3(MI_P / 128, 2), 256, 0, stream>>>(
        x_mi, wWmi, nullptr, nullptr, b_mi, emb_mi, h_mi0, N_MI, 128, 256, 0);
    hgemm_reg<2, true><<<dim3(DI_P / 128, 2), 256, 0, stream>>>(
        x_di, wWdi, nullptr, nullptr, b_di, emb_di, h_di0, N_DI, 128, 128, 0);

    // ---- Layer 1: 128 -> 256, relu ----
    agg_kernel<<<(N_DI + 3) / 4, 256, 0, stream>>>(h_mi0, row_di, csr_di, aggh, 128, N_DI);
    hgemm_reg<2, false><<<dim3(DI_P / 128, 4), 256, 0, stream>>>(
        aggh, wl1md, h_di0, wr1md, bl1_md, nullptr, h_di1, N_DI, 256, 128, 1);
    agg_kernel<<<(N_MI + 3) / 4, 256, 0, stream>>>(h_di0, row_mi, csr_mi, aggh, 128, N_MI);
    hgemm_reg<2, false><<<dim3(MI_P / 128, 4), 256, 0, stream>>>(
        aggh, wl1dm, h_mi0, wr1dm, bl1_dm, nullptr, h_mi1, N_MI, 256, 128, 1);

    // ---- Layer 2: 256 -> 128, relu ----
    agg_kernel<<<(N_DI + 3) / 4, 256, 0, stream>>>(h_mi1, row_di, csr_di, aggh, 256, N_DI);
    hgemm_reg<2, false><<<dim3(DI_P / 128, 2), 256, 0, stream>>>(
        aggh, wl2md, h_di1, wr2md, bl2_md, nullptr, h_di0, N_DI, 128, 256, 1);
    agg_kernel<<<(N_MI + 3) / 4, 256, 0, stream>>>(h_di1, row_mi, csr_mi, aggh, 256, N_MI);
    hgemm_reg<2, false><<<dim3(MI_P / 128, 2), 256, 0, stream>>>(
        aggh, wl2dm, h_mi1, wr2dm, bl2_dm, nullptr, h_mi0, N_MI, 128, 256, 1);

    // ---- Layer 3: 128 -> 64, no relu ----
    agg_kernel<<<(N_DI + 3) / 4, 256, 0, stream>>>(h_mi0, row_di, csr_di, aggh, 128, N_DI);
    hgemm_reg<1, false><<<dim3(DI_P / 64, 1), 256, 0, stream>>>(
        aggh, wl3md, h_di0, wr3md, bl3_md, nullptr, h_di1, N_DI, 64, 128, 0);
    agg_kernel<<<(N_MI + 3) / 4, 256, 0, stream>>>(h_di0, row_mi, csr_mi, aggh, 128, N_MI);
    hgemm_reg<1, false><<<dim3(MI_P / 64, 1), 256, 0, stream>>>(
        aggh, wl3dm, h_mi0, wr3dm, bl3_dm, nullptr, h_mi1, N_MI, 64, 128, 0);

    // ---- classifier ----
    classify_kernel<<<((long)L * 16 + 255) / 256, 256, 0, stream>>>(
        h_mi1, h_di1, label_src, label_dst, out, L);
}

// Round 4
// 1055.530 us; speedup vs baseline: 1.1594x; 1.1594x over previous
//
#include <hip/hip_runtime.h>

#define N_MI 100000
#define N_DI 50000
#define MI_P 100352   // multiple of 256
#define DI_P 50176    // multiple of 256

typedef _Float16 half8  __attribute__((ext_vector_type(8)));
typedef _Float16 half4  __attribute__((ext_vector_type(4)));
typedef float    floatx4 __attribute__((ext_vector_type(4)));

// ---------------------------------------------------------------------------
// CSR build
// ---------------------------------------------------------------------------
__global__ void count_kernel(const int* __restrict__ src, const int* __restrict__ dst,
                             int* deg_mi, int* deg_di, int E) {
    int i = blockIdx.x * blockDim.x + threadIdx.x;
    if (i < E) {
        atomicAdd(&deg_mi[src[i]], 1);
        atomicAdd(&deg_di[dst[i]], 1);
    }
}

__global__ __launch_bounds__(1024) void scan_kernel(const int* __restrict__ deg_di,
                                                    const int* __restrict__ deg_mi,
                                                    int* row_di, int* row_mi) {
    const int* deg;
    int* row;
    int n;
    if (blockIdx.x == 0) { deg = deg_di; row = row_di; n = N_DI; }
    else                 { deg = deg_mi; row = row_mi; n = N_MI; }

    __shared__ int wsum[16];
    int t = threadIdx.x;
    int lane = t & 63;
    int w = t >> 6;
    int carry = 0;

    for (int base = 0; base < n; base += 1024) {
        int i = base + t;
        int v = (i < n) ? deg[i] : 0;
        int x = v;
        #pragma unroll
        for (int off = 1; off < 64; off <<= 1) {
            int y = __shfl_up(x, off, 64);
            if (lane >= off) x += y;
        }
        if (lane == 63) wsum[w] = x;
        __syncthreads();
        if (w == 0 && lane < 16) {
            int s = wsum[lane];
            #pragma unroll
            for (int off = 1; off < 16; off <<= 1) {
                int y = __shfl_up(s, off, 16);
                if (lane >= off) s += y;
            }
            wsum[lane] = s;
        }
        __syncthreads();
        int woff = (w == 0) ? 0 : wsum[w - 1];
        int incl = x + woff;
        if (i < n) row[i] = carry + incl - v;
        carry += wsum[15];
        __syncthreads();
    }
    if (t == 0) row[n] = carry;
}

__global__ void fill_kernel(const int* __restrict__ src, const int* __restrict__ dst,
                            const int* __restrict__ row_mi, const int* __restrict__ row_di,
                            int* cur_mi, int* cur_di, int* csr_mi, int* csr_di, int E) {
    int i = blockIdx.x * blockDim.x + threadIdx.x;
    if (i >= E) return;
    int s = src[i], d = dst[i];
    int p = atomicAdd(&cur_di[d], 1);
    csr_di[row_di[d] + p] = s;
    int q = atomicAdd(&cur_mi[s], 1);
    csr_mi[row_mi[s] + q] = d;
}

// ---------------------------------------------------------------------------
// fp32 -> fp16 converts
// ---------------------------------------------------------------------------
__global__ void cvt_kernel(const float* __restrict__ s, _Float16* __restrict__ d, int n4) {
    int i = blockIdx.x * blockDim.x + threadIdx.x;
    if (i < n4) {
        float4 v = ((const float4*)s)[i];
        half4 h = {(_Float16)v.x, (_Float16)v.y, (_Float16)v.z, (_Float16)v.w};
        ((half4*)d)[i] = h;
    }
}

struct Cvt14 {
    const float* s[14];
    _Float16* d[14];
    int n4[14];
};

__global__ void cvt14_kernel(Cvt14 a) {
    int arr = blockIdx.y;
    int i = blockIdx.x * blockDim.x + threadIdx.x;
    if (i < a.n4[arr]) {
        float4 v = ((const float4*)a.s[arr])[i];
        half4 h = {(_Float16)v.x, (_Float16)v.y, (_Float16)v.z, (_Float16)v.w};
        ((half4*)a.d[arr])[i] = h;
    }
}

// ---------------------------------------------------------------------------
// Mean aggregation: one node per wave. din=128 -> 4 neighbors/pass (16 lanes x
// half8 each); din=256 -> 2 neighbors/pass (32 lanes). fp32 acc, shfl reduce.
// ---------------------------------------------------------------------------
template<int DIN>
__global__ __launch_bounds__(256) void agg2_kernel(const _Float16* __restrict__ hsrc,
                                                   const int* __restrict__ row,
                                                   const int* __restrict__ csr,
                                                   _Float16* __restrict__ out, int n) {
    constexpr int LPR = DIN / 8;    // lanes per row chunk: 16 or 32
    constexpr int GR  = 64 / LPR;   // neighbor groups per wave: 4 or 2
    int node = blockIdx.x * 4 + (threadIdx.x >> 6);
    if (node >= n) return;
    int lane = threadIdx.x & 63;
    int g = lane / LPR, c = lane % LPR;
    int beg = row[node], end = row[node + 1];
    float acc[8] = {};
    #pragma unroll 2
    for (int j = beg + g; j < end; j += GR) {
        half8 v = *(const half8*)(hsrc + (long)csr[j] * DIN + c * 8);
        #pragma unroll
        for (int e = 0; e < 8; ++e) acc[e] += (float)v[e];
    }
    float inv = 1.f / (float)max(end - beg, 1);
    half8 o;
    #pragma unroll
    for (int e = 0; e < 8; ++e) {
        float s = acc[e];
        s += __shfl_down(s, 32);
        if (GR == 4) s += __shfl_down(s, 16);
        o[e] = (_Float16)(s * inv);
    }
    if (g == 0) *(half8*)(out + (long)node * DIN + c * 8) = o;
}

// ---------------------------------------------------------------------------
// Streaming fp16 MFMA GEMM. Block = 4 waves covering FULL N (NWN 64-col wave
// tiles across N, 4/NWN wave tiles stacked along M; 64 rows per wave).
// B fragments in registers (W panels are L2-resident, <=64KB); A panel
// streamed with a depth-2 pipelined fully-unrolled K loop. No LDS/barriers.
// C = act(A1@W1^T [+ A2@W2^T] + bias [+ Cadd_f32])
// ---------------------------------------------------------------------------
template<int KI>
__device__ __forceinline__ void gpass(const _Float16* __restrict__ A,
                                      const _Float16* __restrict__ W,
                                      long mbase, int n0, int lr, int quad,
                                      floatx4 (&acc)[4][4]) {
    constexpr int K = KI * 32;
    constexpr int KC = (KI > 4) ? 4 : KI;   // B-register chunk (k-iters)
    half8 af[2][4];
    #pragma unroll
    for (int i = 0; i < 4; ++i)
        af[0][i] = *(const half8*)(A + (mbase + i * 16 + lr) * K + quad * 8);
    #pragma unroll
    for (int kc = 0; kc < KI; kc += KC) {
        half8 bf[KC][4];
        #pragma unroll
        for (int t = 0; t < KC; ++t)
            #pragma unroll
            for (int j = 0; j < 4; ++j)
                bf[t][j] = *(const half8*)(W + (long)(n0 + j * 16 + lr) * K + (kc + t) * 32 + quad * 8);
        #pragma unroll
        for (int t = 0; t < KC; ++t) {
            int kk = kc + t;
            if (kk + 1 < KI) {
                #pragma unroll
                for (int i = 0; i < 4; ++i)
                    af[(kk + 1) & 1][i] = *(const half8*)(A + (mbase + i * 16 + lr) * K + (kk + 1) * 32 + quad * 8);
            }
            #pragma unroll
            for (int i = 0; i < 4; ++i)
                #pragma unroll
                for (int j = 0; j < 4; ++j)
                    acc[i][j] = __builtin_amdgcn_mfma_f32_16x16x32_f16(af[kk & 1][i], bf[t][j], acc[i][j], 0, 0, 0);
        }
    }
}

template<int KI, bool DUAL, int NWN>
__global__ __launch_bounds__(256, 2) void hgemm_s(
    const _Float16* __restrict__ A1, const _Float16* __restrict__ W1,
    const _Float16* __restrict__ A2, const _Float16* __restrict__ W2,
    const float* __restrict__ bias, const float* __restrict__ Cadd,
    _Float16* __restrict__ C, int M, int N, int relu)
{
    const int wave = threadIdx.x >> 6, lane = threadIdx.x & 63;
    const int quad = lane >> 4, lr = lane & 15;
    const int n0 = (wave % NWN) * 64;
    const long mbase = (long)blockIdx.x * (64 * (4 / NWN)) + (wave / NWN) * 64;

    floatx4 acc[4][4] = {};

    gpass<KI>(A1, W1, mbase, n0, lr, quad, acc);
    if (DUAL)
        gpass<KI>(A2, W2, mbase, n0, lr, quad, acc);

    // epilogue: C/D layout col = lane&15 (n), row = quad*4+reg (m)
    #pragma unroll
    for (int i = 0; i < 4; ++i) {
        int mb = (int)mbase + i * 16 + quad * 4;
        #pragma unroll
        for (int j = 0; j < 4; ++j) {
            int n = n0 + j * 16 + lr;
            float bn = bias[n];
            #pragma unroll
            for (int r = 0; r < 4; ++r) {
                int m = mb + r;
                if (m < M) {
                    float v = acc[i][j][r] + bn;
                    if (Cadd) v += Cadd[(long)m * N + n];
                    if (relu) v = fmaxf(v, 0.f);
                    C[(long)m * N + n] = (_Float16)v;
                }
            }
        }
    }
}

// ---------------------------------------------------------------------------
// Classifier: out[e] = dot64(h_mi[ls[e]], h_di[ld[e]]), fp16 in, fp32 out
// ---------------------------------------------------------------------------
__global__ void classify_kernel(const _Float16* __restrict__ hmi, const _Float16* __restrict__ hdi,
                                const int* __restrict__ ls, const int* __restrict__ ld,
                                float* __restrict__ out, int L) {
    long idx = (long)blockIdx.x * blockDim.x + threadIdx.x;
    int e = (int)(idx >> 4), q = (int)(idx & 15);
    if (e >= L) return;
    const half4* ra = (const half4*)(hmi + (long)ls[e] * 64);
    const half4* rb = (const half4*)(hdi + (long)ld[e] * 64);
    half4 a = ra[q], b = rb[q];
    float s = (float)a.x * (float)b.x + (float)a.y * (float)b.y +
              (float)a.z * (float)b.z + (float)a.w * (float)b.w;
    #pragma unroll
    for (int off = 8; off >= 1; off >>= 1) s += __shfl_down(s, off, 16);
    if (q == 0) out[e] = s;
}

// ---------------------------------------------------------------------------
// Launch
// ---------------------------------------------------------------------------
extern "C" void kernel_launch(void* const* d_in, const int* in_sizes, int n_in,
                              void* d_out, int out_size, void* d_ws, size_t ws_size,
                              hipStream_t stream) {
    const float* x_mi   = (const float*)d_in[0];
    const float* x_di   = (const float*)d_in[1];
    const float* W_mi   = (const float*)d_in[2];
    const float* b_mi   = (const float*)d_in[3];
    const float* W_di   = (const float*)d_in[4];
    const float* b_di   = (const float*)d_in[5];
    const float* emb_mi = (const float*)d_in[6];
    const float* emb_di = (const float*)d_in[7];
    const float* Wl1_md = (const float*)d_in[8];
    const float* bl1_md = (const float*)d_in[9];
    const float* Wr1_md = (const float*)d_in[10];
    const float* Wl1_dm = (const float*)d_in[11];
    const float* bl1_dm = (const float*)d_in[12];
    const float* Wr1_dm = (const float*)d_in[13];
    const float* Wl2_md = (const float*)d_in[14];
    const float* bl2_md = (const float*)d_in[15];
    const float* Wr2_md = (const float*)d_in[16];
    const float* Wl2_dm = (const float*)d_in[17];
    const float* bl2_dm = (const float*)d_in[18];
    const float* Wr2_dm = (const float*)d_in[19];
    const float* Wl3_md = (const float*)d_in[20];
    const float* bl3_md = (const float*)d_in[21];
    const float* Wr3_md = (const float*)d_in[22];
    const float* Wl3_dm = (const float*)d_in[23];
    const float* bl3_dm = (const float*)d_in[24];
    const float* Wr3_dm = (const float*)d_in[25];
    const int* edge_src  = (const int*)d_in[26];
    const int* edge_dst  = (const int*)d_in[27];
    const int* label_src = (const int*)d_in[28];
    const int* label_dst = (const int*)d_in[29];
    const int E = in_sizes[26];
    const int L = in_sizes[28];
    float* out = (float*)d_out;

    // ---- workspace layout (fp16 first, then ints) ----
    _Float16* hp = (_Float16*)d_ws;
    _Float16* xh_mi = hp; hp += (long)MI_P * 256;
    _Float16* xh_di = hp; hp += (long)DI_P * 128;
    _Float16* wWmi  = hp; hp += 128 * 256;
    _Float16* wWdi  = hp; hp += 128 * 128;
    _Float16* wl1md = hp; hp += 256 * 128;
    _Float16* wr1md = hp; hp += 256 * 128;
    _Float16* wl1dm = hp; hp += 256 * 128;
    _Float16* wr1dm = hp; hp += 256 * 128;
    _Float16* wl2md = hp; hp += 128 * 256;
    _Float16* wr2md = hp; hp += 128 * 256;
    _Float16* wl2dm = hp; hp += 128 * 256;
    _Float16* wr2dm = hp; hp += 128 * 256;
    _Float16* wl3md = hp; hp += 64 * 128;
    _Float16* wr3md = hp; hp += 64 * 128;
    _Float16* wl3dm = hp; hp += 64 * 128;
    _Float16* wr3dm = hp; hp += 64 * 128;
    _Float16* h_mi0 = hp; hp += (long)MI_P * 256;
    _Float16* h_mi1 = hp; hp += (long)MI_P * 256;
    _Float16* h_di0 = hp; hp += (long)DI_P * 256;
    _Float16* h_di1 = hp; hp += (long)DI_P * 256;
    _Float16* aggh  = hp; hp += (long)MI_P * 256;

    int* ip = (int*)hp;
    int* deg_di = ip;  ip += N_DI;
    int* deg_mi = ip;  ip += N_MI;
    int* cur_di = ip;  ip += N_DI;
    int* cur_mi = ip;  ip += N_MI;
    int* row_di = ip;  ip += N_DI + 1;
    int* row_mi = ip;  ip += N_MI + 1;
    int* csr_di = ip;  ip += E;
    int* csr_mi = ip;  ip += E;

    // ---- CSR build ----
    hipMemsetAsync(deg_di, 0, (size_t)(2 * (N_DI + N_MI)) * sizeof(int), stream);
    int eb = (E + 255) / 256;
    count_kernel<<<eb, 256, 0, stream>>>(edge_src, edge_dst, deg_mi, deg_di, E);
    scan_kernel<<<2, 1024, 0, stream>>>(deg_di, deg_mi, row_di, row_mi);
    fill_kernel<<<eb, 256, 0, stream>>>(edge_src, edge_dst, row_mi, row_di,
                                        cur_mi, cur_di, csr_mi, csr_di, E);

    // ---- converts ----
    cvt_kernel<<<(N_MI * 256 / 4 + 255) / 256, 256, 0, stream>>>(x_mi, xh_mi, N_MI * 256 / 4);
    cvt_kernel<<<(N_DI * 128 / 4 + 255) / 256, 256, 0, stream>>>(x_di, xh_di, N_DI * 128 / 4);
    Cvt14 cv;
    const float* srcs[14] = {W_mi, W_di, Wl1_md, Wr1_md, Wl1_dm, Wr1_dm,
                             Wl2_md, Wr2_md, Wl2_dm, Wr2_dm, Wl3_md, Wr3_md, Wl3_dm, Wr3_dm};
    _Float16* dsts[14] = {wWmi, wWdi, wl1md, wr1md, wl1dm, wr1dm,
                          wl2md, wr2md, wl2dm, wr2dm, wl3md, wr3md, wl3dm, wr3dm};
    int ns[14] = {32768, 16384, 32768, 32768, 32768, 32768,
                  32768, 32768, 32768, 32768, 8192, 8192, 8192, 8192};
    for (int i = 0; i < 14; ++i) { cv.s[i] = srcs[i]; cv.d[i] = dsts[i]; cv.n4[i] = ns[i] / 4; }
    cvt14_kernel<<<dim3(32, 14), 256, 0, stream>>>(cv);

    // ---- init: h0 = x @ W^T + b + emb ----
    hgemm_s<8, false, 2><<<MI_P / 128, 256, 0, stream>>>(
        xh_mi, wWmi, nullptr, nullptr, b_mi, emb_mi, h_mi0, N_MI, 128, 0);
    hgemm_s<4, false, 2><<<DI_P / 128, 256, 0, stream>>>(
        xh_di, wWdi, nullptr, nullptr, b_di, emb_di, h_di0, N_DI, 128, 0);

    // ---- Layer 1: 128 -> 256, relu ----
    agg2_kernel<128><<<(N_DI + 3) / 4, 256, 0, stream>>>(h_mi0, row_di, csr_di, aggh, N_DI);
    hgemm_s<4, true, 4><<<DI_P / 64, 256, 0, stream>>>(
        aggh, wl1md, h_di0, wr1md, bl1_md, nullptr, h_di1, N_DI, 256, 1);
    agg2_kernel<128><<<(N_MI + 3) / 4, 256, 0, stream>>>(h_di0, row_mi, csr_mi, aggh, N_MI);
    hgemm_s<4, true, 4><<<MI_P / 64, 256, 0, stream>>>(
        aggh, wl1dm, h_mi0, wr1dm, bl1_dm, nullptr, h_mi1, N_MI, 256, 1);

    // ---- Layer 2: 256 -> 128, relu ----
    agg2_kernel<256><<<(N_DI + 3) / 4, 256, 0, stream>>>(h_mi1, row_di, csr_di, aggh, N_DI);
    hgemm_s<8, true, 2><<<DI_P / 128, 256, 0, stream>>>(
        aggh, wl2md, h_di1, wr2md, bl2_md, nullptr, h_di0, N_DI, 128, 1);
    agg2_kernel<256><<<(N_MI + 3) / 4, 256, 0, stream>>>(h_di1, row_mi, csr_mi, aggh, N_MI);
    hgemm_s<8, true, 2><<<MI_P / 128, 256, 0, stream>>>(
        aggh, wl2dm, h_mi1, wr2dm, bl2_dm, nullptr, h_mi0, N_MI, 128, 1);

    // ---- Layer 3: 128 -> 64, no relu ----
    agg2_kernel<128><<<(N_DI + 3) / 4, 256, 0, stream>>>(h_mi0, row_di, csr_di, aggh, N_DI);
    hgemm_s<4, true, 1><<<DI_P / 256, 256, 0, stream>>>(
        aggh, wl3md, h_di0, wr3md, bl3_md, nullptr, h_di1, N_DI, 64, 0);
    agg2_kernel<128><<<(N_MI + 3) / 4, 256, 0, stream>>>(h_di0, row_mi, csr_mi, aggh, N_MI);
    hgemm_s<4, true, 1><<<MI_P / 256, 256, 0, stream>>>(
        aggh, wl3dm, h_mi0, wr3dm, bl3_dm, nullptr, h_mi1, N_MI, 64, 0);

    // ---- classifier ----
    classify_kernel<<<((long)L * 16 + 255) / 256, 256, 0, stream>>>(
        h_mi1, h_di1, label_src, label_dst, out, L);
}